// Round 4
// baseline (1024.347 us; speedup 1.0000x reference)
//
#include <hip/hip_runtime.h>
#include <hip/hip_bf16.h>

typedef __hip_bfloat16 bf16;
typedef short s16x8 __attribute__((ext_vector_type(8)));
typedef float f32x4 __attribute__((ext_vector_type(4)));

// ---------------- workspace layout (bytes) ----------------
// Xp    (bf16,  [512][256 px][512 ci])     @ 0           size 134,217,728
// cf_t  (float, [2][14][14][256])          @ 134,217,728 size 401,408
// Wp    (bf16,  [9][256][512])             @ 134,619,136 size 2,359,296
// scale (float, [256])                     @ 136,978,432
// shift (float, [256])                     @ 136,979,456
// (Xp first so k_conv's bounded tap overrun on n=511 lands in cf_t, not OOB)
#define OFF_CFT   (134217728)
#define OFF_WP    (134619136)
#define OFF_SCALE (136978432)
#define OFF_SHIFT (136979456)

// ---------------- kernel 1: bilinear resize features -> cf_t[b][y][x][c] ----------------
__global__ void k_resize(const float* __restrict__ feat, float* __restrict__ cf_t) {
    int idx = blockIdx.x * 256 + threadIdx.x;      // 2*14*14*256 = 100352
    if (idx >= 2 * 14 * 14 * 256) return;
    int c  = idx & 255;
    int sp = idx >> 8;            // b*196 + y*14 + x
    int x  = sp % 14;
    int y  = (sp / 14) % 14;
    int b  = sp / 196;
    const float sy = 96.0f / 14.0f, sx = 128.0f / 14.0f;
    float s = fmaxf(((float)y + 0.5f) * sy - 0.5f, 0.0f);
    int y0 = min((int)floorf(s), 95); int y1 = min(y0 + 1, 95); float wy = s - (float)y0;
    float t = fmaxf(((float)x + 0.5f) * sx - 0.5f, 0.0f);
    int x0 = min((int)floorf(t), 127); int x1 = min(x0 + 1, 127); float wx = t - (float)x0;
    const float* f = feat + (size_t)(b * 256 + c) * 96 * 128;
    float v00 = f[y0 * 128 + x0], v01 = f[y0 * 128 + x1];
    float v10 = f[y1 * 128 + x0], v11 = f[y1 * 128 + x1];
    float r0 = v00 * (1.f - wy) + v10 * wy;
    float r1 = v01 * (1.f - wy) + v11 * wy;
    cf_t[idx] = r0 * (1.f - wx) + r1 * wx;
}

// ---------------- kernel 2: pack weights + fold BN ----------------
__global__ void k_packw(const float* __restrict__ w, const float* __restrict__ cb,
                        const float* __restrict__ g, const float* __restrict__ be,
                        const float* __restrict__ mean, const float* __restrict__ var,
                        bf16* __restrict__ Wp, float* __restrict__ scale, float* __restrict__ shift) {
    int idx = blockIdx.x * 256 + threadIdx.x;      // 9*256*512 = 1,179,648
    if (idx < 256) {
        float inv = rsqrtf(var[idx] + 1e-5f);
        float sc = g[idx] * inv;
        scale[idx] = sc;
        shift[idx] = (cb[idx] - mean[idx]) * sc + be[idx];
    }
    if (idx >= 9 * 256 * 512) return;
    int ci  = idx & 511;
    int co  = (idx >> 9) & 255;
    int tap = idx >> 17;
    // conv_w is [co][ci][kh][kw]; Wp is [tap][co][ci]
    Wp[idx] = __float2bfloat16(w[(co * 512 + ci) * 9 + tap]);
}

// ---------------- kernel 3: build padded transposed conv input Xp[n][py*16+px][ci] ----------------
__global__ __launch_bounds__(256) void k_build(const float* __restrict__ mask,
                                               const float* __restrict__ boxes,
                                               const float* __restrict__ cf_t,
                                               bf16* __restrict__ Xp) {
    int n = blockIdx.x;          // 0..511
    int c = threadIdx.x;         // 0..255
    bf16* Xn = Xp + (size_t)n * 256 * 512;

    // zero border pixels (rows/cols 0 and 15 of the 16x16 padded grid), both channel halves
    for (int p = 0; p < 256; ++p) {
        int py = p >> 4, px = p & 15;
        if (py == 0 || py == 15 || px == 0 || px == 15) {
            Xn[p * 512 + c]       = __float2bfloat16(0.f);
            Xn[p * 512 + 256 + c] = __float2bfloat16(0.f);
        }
    }

    __shared__ int   YL0[14], YL1[14], XL0[14], XL1[14];
    __shared__ float WY[14], WX[14];

    int b = n >> 8, i = n & 255;
    const float* pb = boxes + (b * 256 + i) * 4;
    int xa = (int)(pb[0] * 0.125f), ya = (int)(pb[1] * 0.125f);
    int xb = (int)(pb[2] * 0.125f), yb = (int)(pb[3] * 0.125f);
    if (xb - xa < 1) { if (xb == 14) xa -= 1; else xb += 1; }
    if (yb - ya < 1) { if (yb == 14) ya -= 1; else yb += 1; }

    if (c < 14) {                       // y-axis LUT, oy = c
        float nf = (float)(yb - ya);
        float s = fmaxf(((float)c + 0.5f) * nf / 14.0f - 0.5f, 0.0f);
        int i0 = min((int)floorf(s), yb - ya - 1);
        int i1 = min(i0 + 1, yb - ya - 1);
        YL0[c] = ya + i0; YL1[c] = ya + i1; WY[c] = s - (float)i0;
    } else if (c < 28) {                // x-axis LUT, ox = c-14
        int ox = c - 14;
        float nf = (float)(xb - xa);
        float s = fmaxf(((float)ox + 0.5f) * nf / 14.0f - 0.5f, 0.0f);
        int i0 = min((int)floorf(s), xb - xa - 1);
        int i1 = min(i0 + 1, xb - xa - 1);
        XL0[ox] = xa + i0; XL1[ox] = xa + i1; WX[ox] = s - (float)i0;
    }
    __syncthreads();

    const float* mrow = mask + (size_t)(n * 256 + c) * 196;
    const float* cfb  = cf_t + (size_t)b * 196 * 256;
    for (int s = 0; s < 196; ++s) {
        int oy = s / 14, ox = s % 14;
        int prow = (oy + 1) * 16 + (ox + 1);
        // channels 0..255: mask_features (transpose; line-amortized strided read)
        Xn[prow * 512 + c] = __float2bfloat16(mrow[s]);
        // channels 256..511: crop-resize from cf_t (coalesced gathers along c)
        int Y0 = YL0[oy], Y1 = YL1[oy], X0 = XL0[ox], X1 = XL1[ox];
        float wy = WY[oy], wx = WX[ox];
        float v00 = cfb[(Y0 * 14 + X0) * 256 + c];
        float v01 = cfb[(Y0 * 14 + X1) * 256 + c];
        float v10 = cfb[(Y1 * 14 + X0) * 256 + c];
        float v11 = cfb[(Y1 * 14 + X1) * 256 + c];
        float r0 = v00 * (1.f - wy) + v10 * wy;
        float r1 = v01 * (1.f - wy) + v11 * wy;
        Xn[prow * 512 + 256 + c] = __float2bfloat16(r0 * (1.f - wx) + r1 * wx);
    }
}

// ---------------- kernel 4: implicit-GEMM conv + bias/BN/ReLU ----------------
// block = 512 threads = 8 waves (4 co-waves x 2 px-waves); block tile = 256co x 224px (one batch n)
__global__ __launch_bounds__(512, 2) void k_conv(const bf16* __restrict__ Wp,
                                                 const bf16* __restrict__ Xp,
                                                 const float* __restrict__ scale,
                                                 const float* __restrict__ shift,
                                                 float* __restrict__ out) {
    int n   = blockIdx.x;
    int tid = threadIdx.x;
    int w = tid >> 6, l = tid & 63;
    int wm = w >> 1, wn = w & 1;
    int lr = l & 15, lk = l >> 4;
    int co_base = wm * 64;
    int px_base = wn * 112;

    const bf16* Xn = Xp + (size_t)n * 256 * 512;

    int aoff[4], boff[7];
#pragma unroll
    for (int m = 0; m < 4; ++m) aoff[m] = (co_base + m * 16 + lr) * 512 + lk * 8;
#pragma unroll
    for (int j = 0; j < 7; ++j) boff[j] = (px_base + j * 16 + lr) * 512 + lk * 8;

    f32x4 acc[4][7];
#pragma unroll
    for (int m = 0; m < 4; ++m)
#pragma unroll
        for (int j = 0; j < 7; ++j) acc[m][j] = f32x4{0.f, 0.f, 0.f, 0.f};

    for (int kh = 0; kh < 3; ++kh)
        for (int kw = 0; kw < 3; ++kw) {
            const bf16* Wt = Wp + (kh * 3 + kw) * (256 * 512);
            const bf16* Xt = Xn + (kh * 16 + kw) * 512;   // linear tap offset in padded grid
#pragma unroll 2
            for (int k = 0; k < 16; ++k) {
                int kc = k * 32;
                s16x8 a[4], b[7];
#pragma unroll
                for (int m = 0; m < 4; ++m) a[m] = *(const s16x8*)(Wt + aoff[m] + kc);
#pragma unroll
                for (int j = 0; j < 7; ++j) b[j] = *(const s16x8*)(Xt + boff[j] + kc);
#pragma unroll
                for (int m = 0; m < 4; ++m)
#pragma unroll
                    for (int j = 0; j < 7; ++j)
                        acc[m][j] = __builtin_amdgcn_mfma_f32_16x16x32_bf16(a[m], b[j], acc[m][j], 0, 0, 0);
            }
        }

    // epilogue: y = relu(acc*scale + shift); D layout: col=lane&15, row=(lane>>4)*4+r
#pragma unroll
    for (int m = 0; m < 4; ++m) {
        f32x4 sc = *(const f32x4*)(scale + co_base + m * 16 + lk * 4);
        f32x4 sh = *(const f32x4*)(shift + co_base + m * 16 + lk * 4);
#pragma unroll
        for (int j = 0; j < 7; ++j) {
            int px = px_base + j * 16 + lr;
            int pxx = px & 15, py = px >> 4;
            if (pxx < 14) {
                float* op = out + (size_t)(n * 256 + co_base + m * 16 + lk * 4) * 196 + py * 14 + pxx;
#pragma unroll
                for (int r = 0; r < 4; ++r) {
                    float y = acc[m][j][r] * sc[r] + sh[r];
                    op[r * 196] = fmaxf(y, 0.f);
                }
            }
        }
    }
}

extern "C" void kernel_launch(void* const* d_in, const int* in_sizes, int n_in,
                              void* d_out, int out_size, void* d_ws, size_t ws_size,
                              hipStream_t stream) {
    const float* features = (const float*)d_in[0];
    const float* boxes    = (const float*)d_in[1];
    const float* mask     = (const float*)d_in[2];
    const float* conv_w   = (const float*)d_in[3];
    const float* conv_b   = (const float*)d_in[4];
    const float* bn_g     = (const float*)d_in[5];
    const float* bn_b     = (const float*)d_in[6];
    const float* bn_m     = (const float*)d_in[7];
    const float* bn_v     = (const float*)d_in[8];

    char* base   = (char*)d_ws;
    bf16*  Xp    = (bf16*)(base);
    float* cf_t  = (float*)(base + OFF_CFT);
    bf16*  Wp    = (bf16*)(base + OFF_WP);
    float* scale = (float*)(base + OFF_SCALE);
    float* shift = (float*)(base + OFF_SHIFT);
    float* out   = (float*)d_out;

    k_resize<<<392, 256, 0, stream>>>(features, cf_t);
    k_packw<<<4608, 256, 0, stream>>>(conv_w, conv_b, bn_g, bn_b, bn_m, bn_v, Wp, scale, shift);
    k_build<<<512, 256, 0, stream>>>(mask, boxes, cf_t, Xp);
    k_conv<<<512, 512, 0, stream>>>(Wp, Xp, scale, shift, out);
}

// Round 5
// 1017.429 us; speedup vs baseline: 1.0068x; 1.0068x over previous
//
#include <hip/hip_runtime.h>
#include <hip/hip_bf16.h>

typedef __hip_bfloat16 bf16;
typedef short s16x8 __attribute__((ext_vector_type(8)));
typedef float f32x4 __attribute__((ext_vector_type(4)));

// ---------------- workspace layout (bytes) ----------------
// Xp    (bf16,  [512][256 px][512 ci])     @ 0           size 134,217,728
// cf_t  (float, [2][14][14][256])          @ 134,217,728 size 401,408
// Wp    (bf16,  [9][256][512])             @ 134,619,136 size 2,359,296
// scale (float, [256])                     @ 136,978,432
// shift (float, [256])                     @ 136,979,456
// (Xp first so k_conv's bounded tap overrun on n=511 lands in cf_t, not OOB)
#define OFF_CFT   (134217728)
#define OFF_WP    (134619136)
#define OFF_SCALE (136978432)
#define OFF_SHIFT (136979456)

// ---------------- kernel 1: bilinear resize features -> cf_t[b][y][x][c] ----------------
__global__ void k_resize(const float* __restrict__ feat, float* __restrict__ cf_t) {
    int idx = blockIdx.x * 256 + threadIdx.x;      // 2*14*14*256 = 100352
    if (idx >= 2 * 14 * 14 * 256) return;
    int c  = idx & 255;
    int sp = idx >> 8;            // b*196 + y*14 + x
    int x  = sp % 14;
    int y  = (sp / 14) % 14;
    int b  = sp / 196;
    const float sy = 96.0f / 14.0f, sx = 128.0f / 14.0f;
    float s = fmaxf(((float)y + 0.5f) * sy - 0.5f, 0.0f);
    int y0 = min((int)floorf(s), 95); int y1 = min(y0 + 1, 95); float wy = s - (float)y0;
    float t = fmaxf(((float)x + 0.5f) * sx - 0.5f, 0.0f);
    int x0 = min((int)floorf(t), 127); int x1 = min(x0 + 1, 127); float wx = t - (float)x0;
    const float* f = feat + (size_t)(b * 256 + c) * 96 * 128;
    float v00 = f[y0 * 128 + x0], v01 = f[y0 * 128 + x1];
    float v10 = f[y1 * 128 + x0], v11 = f[y1 * 128 + x1];
    float r0 = v00 * (1.f - wy) + v10 * wy;
    float r1 = v01 * (1.f - wy) + v11 * wy;
    cf_t[idx] = r0 * (1.f - wx) + r1 * wx;
}

// ---------------- kernel 2: pack weights + fold BN ----------------
__global__ void k_packw(const float* __restrict__ w, const float* __restrict__ cb,
                        const float* __restrict__ g, const float* __restrict__ be,
                        const float* __restrict__ mean, const float* __restrict__ var,
                        bf16* __restrict__ Wp, float* __restrict__ scale, float* __restrict__ shift) {
    int idx = blockIdx.x * 256 + threadIdx.x;      // 9*256*512 = 1,179,648
    if (idx < 256) {
        float inv = rsqrtf(var[idx] + 1e-5f);
        float sc = g[idx] * inv;
        scale[idx] = sc;
        shift[idx] = (cb[idx] - mean[idx]) * sc + be[idx];
    }
    if (idx >= 9 * 256 * 512) return;
    int ci  = idx & 511;
    int co  = (idx >> 9) & 255;
    int tap = idx >> 17;
    // conv_w is [co][ci][kh][kw]; Wp is [tap][co][ci]
    Wp[idx] = __float2bfloat16(w[(co * 512 + ci) * 9 + tap]);
}

// ---------------- kernel 3: build padded transposed conv input Xp[n][py*16+px][ci] ----------------
__global__ __launch_bounds__(256) void k_build(const float* __restrict__ mask,
                                               const float* __restrict__ boxes,
                                               const float* __restrict__ cf_t,
                                               bf16* __restrict__ Xp) {
    int n = blockIdx.x;          // 0..511
    int c = threadIdx.x;         // 0..255
    bf16* Xn = Xp + (size_t)n * 256 * 512;

    // zero border pixels (rows/cols 0 and 15 of the 16x16 padded grid), both channel halves
    for (int p = 0; p < 256; ++p) {
        int py = p >> 4, px = p & 15;
        if (py == 0 || py == 15 || px == 0 || px == 15) {
            Xn[p * 512 + c]       = __float2bfloat16(0.f);
            Xn[p * 512 + 256 + c] = __float2bfloat16(0.f);
        }
    }

    __shared__ int   YL0[14], YL1[14], XL0[14], XL1[14];
    __shared__ float WY[14], WX[14];

    int b = n >> 8, i = n & 255;
    const float* pb = boxes + (b * 256 + i) * 4;
    int xa = (int)(pb[0] * 0.125f), ya = (int)(pb[1] * 0.125f);
    int xb = (int)(pb[2] * 0.125f), yb = (int)(pb[3] * 0.125f);
    if (xb - xa < 1) { if (xb == 14) xa -= 1; else xb += 1; }
    if (yb - ya < 1) { if (yb == 14) ya -= 1; else yb += 1; }

    if (c < 14) {                       // y-axis LUT, oy = c
        float nf = (float)(yb - ya);
        float s = fmaxf(((float)c + 0.5f) * nf / 14.0f - 0.5f, 0.0f);
        int i0 = min((int)floorf(s), yb - ya - 1);
        int i1 = min(i0 + 1, yb - ya - 1);
        YL0[c] = ya + i0; YL1[c] = ya + i1; WY[c] = s - (float)i0;
    } else if (c < 28) {                // x-axis LUT, ox = c-14
        int ox = c - 14;
        float nf = (float)(xb - xa);
        float s = fmaxf(((float)ox + 0.5f) * nf / 14.0f - 0.5f, 0.0f);
        int i0 = min((int)floorf(s), xb - xa - 1);
        int i1 = min(i0 + 1, xb - xa - 1);
        XL0[ox] = xa + i0; XL1[ox] = xa + i1; WX[ox] = s - (float)i0;
    }
    __syncthreads();

    const float* mrow = mask + (size_t)(n * 256 + c) * 196;
    const float* cfb  = cf_t + (size_t)b * 196 * 256;
    for (int s = 0; s < 196; ++s) {
        int oy = s / 14, ox = s % 14;
        int prow = (oy + 1) * 16 + (ox + 1);
        // channels 0..255: mask_features (transpose; line-amortized strided read)
        Xn[prow * 512 + c] = __float2bfloat16(mrow[s]);
        // channels 256..511: crop-resize from cf_t (coalesced gathers along c)
        int Y0 = YL0[oy], Y1 = YL1[oy], X0 = XL0[ox], X1 = XL1[ox];
        float wy = WY[oy], wx = WX[ox];
        float v00 = cfb[(Y0 * 14 + X0) * 256 + c];
        float v01 = cfb[(Y0 * 14 + X1) * 256 + c];
        float v10 = cfb[(Y1 * 14 + X0) * 256 + c];
        float v11 = cfb[(Y1 * 14 + X1) * 256 + c];
        float r0 = v00 * (1.f - wy) + v10 * wy;
        float r1 = v01 * (1.f - wy) + v11 * wy;
        Xn[prow * 512 + 256 + c] = __float2bfloat16(r0 * (1.f - wx) + r1 * wx);
    }
}

// ---------------- kernel 4: implicit-GEMM conv + bias/BN/ReLU ----------------
// block = 512 threads = 8 waves (4 co-waves x 2 px-waves); block tile = 256co x 224px (one batch n)
// Loop order: k-step OUTER, 9 taps INNER — per-k-step Xn footprint is ~258 rows x 64B
// (~16.5 KB), and tap row-sets overlap, so the 9 tap re-reads are L1/L2 hits instead of
// the 9x HBM re-stream measured in round 4 (FETCH_SIZE 988 MB, MfmaUtil 14.6%).
__global__ __launch_bounds__(512, 2) void k_conv(const bf16* __restrict__ Wp,
                                                 const bf16* __restrict__ Xp,
                                                 const float* __restrict__ scale,
                                                 const float* __restrict__ shift,
                                                 float* __restrict__ out) {
    int n   = blockIdx.x;
    int tid = threadIdx.x;
    int w = tid >> 6, l = tid & 63;
    int wm = w >> 1, wn = w & 1;
    int lr = l & 15, lk = l >> 4;
    int co_base = wm * 64;
    int px_base = wn * 112;

    const bf16* Xn = Xp + (size_t)n * 256 * 512;

    int aoff[4], boff[7];
#pragma unroll
    for (int m = 0; m < 4; ++m) aoff[m] = (co_base + m * 16 + lr) * 512 + lk * 8;
#pragma unroll
    for (int j = 0; j < 7; ++j) boff[j] = (px_base + j * 16 + lr) * 512 + lk * 8;

    f32x4 acc[4][7];
#pragma unroll
    for (int m = 0; m < 4; ++m)
#pragma unroll
        for (int j = 0; j < 7; ++j) acc[m][j] = f32x4{0.f, 0.f, 0.f, 0.f};

#pragma unroll 1
    for (int k = 0; k < 16; ++k) {
        int kc = k * 32;
#pragma unroll
        for (int kh = 0; kh < 3; ++kh)
#pragma unroll
            for (int kw = 0; kw < 3; ++kw) {
                const bf16* Wt = Wp + (kh * 3 + kw) * (256 * 512) + kc;
                const bf16* Xt = Xn + (kh * 16 + kw) * 512 + kc;   // linear tap offset in padded grid
                s16x8 a[4], b[7];
#pragma unroll
                for (int m = 0; m < 4; ++m) a[m] = *(const s16x8*)(Wt + aoff[m]);
#pragma unroll
                for (int j = 0; j < 7; ++j) b[j] = *(const s16x8*)(Xt + boff[j]);
#pragma unroll
                for (int m = 0; m < 4; ++m)
#pragma unroll
                    for (int j = 0; j < 7; ++j)
                        acc[m][j] = __builtin_amdgcn_mfma_f32_16x16x32_bf16(a[m], b[j], acc[m][j], 0, 0, 0);
            }
    }

    // epilogue: y = relu(acc*scale + shift); D layout: col=lane&15, row=(lane>>4)*4+r
#pragma unroll
    for (int m = 0; m < 4; ++m) {
        f32x4 sc = *(const f32x4*)(scale + co_base + m * 16 + lk * 4);
        f32x4 sh = *(const f32x4*)(shift + co_base + m * 16 + lk * 4);
#pragma unroll
        for (int j = 0; j < 7; ++j) {
            int px = px_base + j * 16 + lr;
            int pxx = px & 15, py = px >> 4;
            if (pxx < 14) {
                float* op = out + (size_t)(n * 256 + co_base + m * 16 + lk * 4) * 196 + py * 14 + pxx;
#pragma unroll
                for (int r = 0; r < 4; ++r) {
                    float y = acc[m][j][r] * sc[r] + sh[r];
                    op[r * 196] = fmaxf(y, 0.f);
                }
            }
        }
    }
}

extern "C" void kernel_launch(void* const* d_in, const int* in_sizes, int n_in,
                              void* d_out, int out_size, void* d_ws, size_t ws_size,
                              hipStream_t stream) {
    const float* features = (const float*)d_in[0];
    const float* boxes    = (const float*)d_in[1];
    const float* mask     = (const float*)d_in[2];
    const float* conv_w   = (const float*)d_in[3];
    const float* conv_b   = (const float*)d_in[4];
    const float* bn_g     = (const float*)d_in[5];
    const float* bn_b     = (const float*)d_in[6];
    const float* bn_m     = (const float*)d_in[7];
    const float* bn_v     = (const float*)d_in[8];

    char* base   = (char*)d_ws;
    bf16*  Xp    = (bf16*)(base);
    float* cf_t  = (float*)(base + OFF_CFT);
    bf16*  Wp    = (bf16*)(base + OFF_WP);
    float* scale = (float*)(base + OFF_SCALE);
    float* shift = (float*)(base + OFF_SHIFT);
    float* out   = (float*)d_out;

    k_resize<<<392, 256, 0, stream>>>(features, cf_t);
    k_packw<<<4608, 256, 0, stream>>>(conv_w, conv_b, bn_g, bn_b, bn_m, bn_v, Wp, scale, shift);
    k_build<<<512, 256, 0, stream>>>(mask, boxes, cf_t, Xp);
    k_conv<<<512, 512, 0, stream>>>(Wp, Xp, scale, shift, out);
}

// Round 6
// 808.455 us; speedup vs baseline: 1.2670x; 1.2585x over previous
//
#include <hip/hip_runtime.h>
#include <hip/hip_bf16.h>

typedef __hip_bfloat16 bf16;
typedef short s16x8 __attribute__((ext_vector_type(8)));
typedef float f32x4 __attribute__((ext_vector_type(4)));

// ---------------- workspace layout (bytes) ----------------
// cf_t  (float, [2][14][14][256])      @ 0          401,408
// Wp    (bf16,  [9][256][512])         @ 401,408    2,359,296
// scale (float,[256]) @ 2,760,704 ; shift @ 2,761,728
// Xq    (bf16, [512 n][16 k][258 rows][32ci] pre-swizzled, 64B/row pitch)
//       @ 2,762,752  size 512*16*16,512 = 135,266,304   (ends ~138.0 MB)
#define OFF_WP    401408
#define OFF_SCALE 2760704
#define OFF_SHIFT 2761728
#define OFF_XQ    2762752
#define XQ_SLICE  16512   // 258 rows * 64 B, 16B-divisible

// swizzle: byte ^= ((row>>1)&3)<<4  -> 16 consecutive rows hit 8 distinct 16B
// slots per 128B window => 2-way LDS access (free, m136). Writer (k_build) and
// reader (k_conv) use the same involution; DMA dest stays linear (rule #21).

// ---------------- kernel 1: bilinear resize features -> cf_t[b][y][x][c] ----------------
__global__ void k_resize(const float* __restrict__ feat, float* __restrict__ cf_t) {
    int idx = blockIdx.x * 256 + threadIdx.x;      // 2*14*14*256 = 100352
    if (idx >= 2 * 14 * 14 * 256) return;
    int c  = idx & 255;
    int sp = idx >> 8;
    int x  = sp % 14;
    int y  = (sp / 14) % 14;
    int b  = sp / 196;
    const float sy = 96.0f / 14.0f, sx = 128.0f / 14.0f;
    float s = fmaxf(((float)y + 0.5f) * sy - 0.5f, 0.0f);
    int y0 = min((int)floorf(s), 95); int y1 = min(y0 + 1, 95); float wy = s - (float)y0;
    float t = fmaxf(((float)x + 0.5f) * sx - 0.5f, 0.0f);
    int x0 = min((int)floorf(t), 127); int x1 = min(x0 + 1, 127); float wx = t - (float)x0;
    const float* f = feat + (size_t)(b * 256 + c) * 96 * 128;
    float v00 = f[y0 * 128 + x0], v01 = f[y0 * 128 + x1];
    float v10 = f[y1 * 128 + x0], v11 = f[y1 * 128 + x1];
    float r0 = v00 * (1.f - wy) + v10 * wy;
    float r1 = v01 * (1.f - wy) + v11 * wy;
    cf_t[idx] = r0 * (1.f - wx) + r1 * wx;
}

// ---------------- kernel 2: pack weights + fold BN (Wp[tap][co][ci]) ----------------
__global__ void k_packw(const float* __restrict__ w, const float* __restrict__ cb,
                        const float* __restrict__ g, const float* __restrict__ be,
                        const float* __restrict__ mean, const float* __restrict__ var,
                        bf16* __restrict__ Wp, float* __restrict__ scale, float* __restrict__ shift) {
    int idx = blockIdx.x * 256 + threadIdx.x;      // 9*256*512
    if (idx < 256) {
        float inv = rsqrtf(var[idx] + 1e-5f);
        float sc = g[idx] * inv;
        scale[idx] = sc;
        shift[idx] = (cb[idx] - mean[idx]) * sc + be[idx];
    }
    if (idx >= 9 * 256 * 512) return;
    int ci  = idx & 511;
    int co  = (idx >> 9) & 255;
    int tap = idx >> 17;
    Wp[idx] = __float2bfloat16(w[(co * 512 + ci) * 9 + tap]);
}

// ---------------- kernel 3: build pre-swizzled per-(n,k) B slices ----------------
__global__ __launch_bounds__(256) void k_build(const float* __restrict__ mask,
                                               const float* __restrict__ boxes,
                                               const float* __restrict__ cf_t,
                                               char* __restrict__ Xq) {
    int n = blockIdx.x, c = threadIdx.x;
    char* Xn = Xq + (size_t)n * (16 * XQ_SLICE);

    // zero the whole per-n region (borders, rows 256-257, unwritten rows)
    { unsigned int* z = (unsigned int*)Xn;
      for (int i = c; i < 16 * XQ_SLICE / 4; i += 256) z[i] = 0u; }

    __shared__ int   YL0[14], YL1[14], XL0[14], XL1[14];
    __shared__ float WY[14], WX[14];

    int b = n >> 8, i = n & 255;
    const float* pb = boxes + (b * 256 + i) * 4;
    int xa = (int)(pb[0] * 0.125f), ya = (int)(pb[1] * 0.125f);
    int xb = (int)(pb[2] * 0.125f), yb = (int)(pb[3] * 0.125f);
    if (xb - xa < 1) { if (xb == 14) xa -= 1; else xb += 1; }
    if (yb - ya < 1) { if (yb == 14) ya -= 1; else yb += 1; }

    if (c < 14) {
        float nf = (float)(yb - ya);
        float s = fmaxf(((float)c + 0.5f) * nf / 14.0f - 0.5f, 0.0f);
        int i0 = min((int)floorf(s), yb - ya - 1);
        int i1 = min(i0 + 1, yb - ya - 1);
        YL0[c] = ya + i0; YL1[c] = ya + i1; WY[c] = s - (float)i0;
    } else if (c < 28) {
        int ox = c - 14;
        float nf = (float)(xb - xa);
        float s = fmaxf(((float)ox + 0.5f) * nf / 14.0f - 0.5f, 0.0f);
        int i0 = min((int)floorf(s), xb - xa - 1);
        int i1 = min(i0 + 1, xb - xa - 1);
        XL0[ox] = xa + i0; XL1[ox] = xa + i1; WX[ox] = s - (float)i0;
    }
    __syncthreads();   // covers zero-pass and LUTs

    const float* mrow = mask + (size_t)(n * 256 + c) * 196;
    const float* cfb  = cf_t + (size_t)b * 196 * 256;
    int e2 = (c & 31) * 2;
    char* p0 = Xn + (c >> 5) * XQ_SLICE;          // mask channels: ci = c      -> k = c>>5
    char* p1 = p0 + 8 * XQ_SLICE;                 // crop channels: ci = c+256  -> k = 8+(c>>5)
    for (int s = 0; s < 196; ++s) {
        int oy = s / 14, ox = s % 14;
        int prow = (oy + 1) * 16 + (ox + 1);
        int swz = (prow * 64 + e2) ^ (((prow >> 1) & 3) << 4);
        *(bf16*)(p0 + swz) = __float2bfloat16(mrow[s]);
        int Y0 = YL0[oy], Y1 = YL1[oy], X0 = XL0[ox], X1 = XL1[ox];
        float wy = WY[oy], wx = WX[ox];
        float v00 = cfb[(Y0 * 14 + X0) * 256 + c];
        float v01 = cfb[(Y0 * 14 + X1) * 256 + c];
        float v10 = cfb[(Y1 * 14 + X0) * 256 + c];
        float v11 = cfb[(Y1 * 14 + X1) * 256 + c];
        float r0 = v00 * (1.f - wy) + v10 * wy;
        float r1 = v01 * (1.f - wy) + v11 * wy;
        *(bf16*)(p1 + swz) = __float2bfloat16(r0 * (1.f - wx) + r1 * wx);
    }
}

// ---------------- kernel 4: implicit-GEMM conv, LDS-dbuf B, reg-prefetch A ----------------
// grid 1024: blk -> (n = blk>>1, co-half = blk&1). block = 256 thr = 4 waves
// (2 wm x 2 wn), tile 128co x 224px. K-loop: 16 k-steps (32ci each), one
// barrier per step; 9 taps inner read the SAME staged 258-row slice.
__global__ __launch_bounds__(256, 2) void k_conv(const bf16* __restrict__ Wp,
                                                 const char* __restrict__ Xq,
                                                 const float* __restrict__ scale,
                                                 const float* __restrict__ shift,
                                                 float* __restrict__ out) {
    __shared__ alignas(16) char smem[2][XQ_SLICE];
    int blk = blockIdx.x;
    int n = blk >> 1, cbh = (blk & 1) << 7;
    int tid = threadIdx.x;
    int wv = tid >> 6, l = tid & 63;
    int wm = wv >> 1, wn = wv & 1;
    int lr = l & 15, lk = l >> 4;
    int co_base = cbh + wm * 64;
    int px_base = wn * 112;
    const char* XqN = Xq + (size_t)n * (16 * XQ_SLICE);

    int aoffb[4];
#pragma unroll
    for (int m = 0; m < 4; ++m) aoffb[m] = (co_base + m * 16 + lr) * 512 + lk * 8;
    int rb64[7];
#pragma unroll
    for (int j = 0; j < 7; ++j) rb64[j] = (px_base + j * 16 + lr) << 6;
    int lkx = lk << 4;
    int xts[3];
#pragma unroll
    for (int kw = 0; kw < 3; ++kw) xts[kw] = lkx ^ ((((lr + kw) >> 1) & 3) << 4);

    f32x4 acc[4][7];
#pragma unroll
    for (int m = 0; m < 4; ++m)
#pragma unroll
        for (int j = 0; j < 7; ++j) acc[m][j] = f32x4{0.f, 0.f, 0.f, 0.f};

    s16x8 A0[4], A1[4], A2[4];

#define STAGE(BUF, K) do {                                                        \
        const char* _s = XqN + (K) * XQ_SLICE;                                    \
        char* _d = &smem[BUF][0];                                                 \
        __builtin_amdgcn_global_load_lds(_s + tid * 16,         _d + tid * 16,         16, 0, 0); \
        __builtin_amdgcn_global_load_lds(_s + 4096  + tid * 16, _d + 4096  + tid * 16, 16, 0, 0); \
        __builtin_amdgcn_global_load_lds(_s + 8192  + tid * 16, _d + 8192  + tid * 16, 16, 0, 0); \
        __builtin_amdgcn_global_load_lds(_s + 12288 + tid * 16, _d + 12288 + tid * 16, 16, 0, 0); \
        if (tid < 8)                                                              \
        __builtin_amdgcn_global_load_lds(_s + 16384 + tid * 16, _d + 16384 + tid * 16, 16, 0, 0); \
    } while (0)

#define LOADA(AR, TAP, K) do {                                                    \
        const bf16* _w = Wp + (TAP) * 131072 + (K) * 32;                          \
        AR[0] = *(const s16x8*)(_w + aoffb[0]);                                   \
        AR[1] = *(const s16x8*)(_w + aoffb[1]);                                   \
        AR[2] = *(const s16x8*)(_w + aoffb[2]);                                   \
        AR[3] = *(const s16x8*)(_w + aoffb[3]);                                   \
    } while (0)

#define COMPUTE(TAP, BUF, AR) do {                                                \
        const char* _sb = &smem[BUF][0];                                          \
        int _ab = ((((TAP) / 3) * 16 + (TAP) % 3) << 6) + xts[(TAP) % 3];         \
        s16x8 bfr[7];                                                             \
        _Pragma("unroll")                                                         \
        for (int j = 0; j < 7; ++j) bfr[j] = *(const s16x8*)(_sb + rb64[j] + _ab);\
        _Pragma("unroll")                                                         \
        for (int m = 0; m < 4; ++m)                                               \
            _Pragma("unroll")                                                     \
            for (int j = 0; j < 7; ++j)                                           \
                acc[m][j] = __builtin_amdgcn_mfma_f32_16x16x32_bf16(AR[m], bfr[j], acc[m][j], 0, 0, 0); \
    } while (0)

#define STEPK(K, BUF) do {                                                        \
        if ((K) < 15) STAGE((BUF) ^ 1, (K) + 1);                                  \
        LOADA(A2, 2, (K));  COMPUTE(0, BUF, A0);                                  \
        LOADA(A0, 3, (K));  COMPUTE(1, BUF, A1);                                  \
        LOADA(A1, 4, (K));  COMPUTE(2, BUF, A2);                                  \
        LOADA(A2, 5, (K));  COMPUTE(3, BUF, A0);                                  \
        LOADA(A0, 6, (K));  COMPUTE(4, BUF, A1);                                  \
        LOADA(A1, 7, (K));  COMPUTE(5, BUF, A2);                                  \
        LOADA(A2, 8, (K));  COMPUTE(6, BUF, A0);                                  \
        if ((K) < 15) {                                                           \
            LOADA(A0, 0, (K) + 1); COMPUTE(7, BUF, A1);                           \
            LOADA(A1, 1, (K) + 1); COMPUTE(8, BUF, A2);                           \
        } else {                                                                  \
            COMPUTE(7, BUF, A1);   COMPUTE(8, BUF, A2);                           \
        }                                                                         \
        __syncthreads();                                                          \
    } while (0)

    // prologue
    STAGE(0, 0);
    LOADA(A0, 0, 0);
    LOADA(A1, 1, 0);
    __syncthreads();   // implicit vmcnt(0) drain makes buf0 + A0/A1 ready

#pragma unroll 1
    for (int kk = 0; kk < 16; kk += 2) {
        STEPK(kk, 0);
        STEPK(kk + 1, 1);
    }

    // epilogue: y = relu(acc*scale + shift); D layout: col=lane&15, row=(lane>>4)*4+r
#pragma unroll
    for (int m = 0; m < 4; ++m) {
        f32x4 sc = *(const f32x4*)(scale + co_base + m * 16 + lk * 4);
        f32x4 sh = *(const f32x4*)(shift + co_base + m * 16 + lk * 4);
#pragma unroll
        for (int j = 0; j < 7; ++j) {
            int px = px_base + j * 16 + lr;
            int pxx = px & 15, py = px >> 4;
            if (pxx < 14) {
                float* op = out + (size_t)(n * 256 + co_base + m * 16 + lk * 4) * 196 + py * 14 + pxx;
#pragma unroll
                for (int r = 0; r < 4; ++r) {
                    float y = acc[m][j][r] * sc[r] + sh[r];
                    op[r * 196] = fmaxf(y, 0.f);
                }
            }
        }
    }
#undef STAGE
#undef LOADA
#undef COMPUTE
#undef STEPK
}

extern "C" void kernel_launch(void* const* d_in, const int* in_sizes, int n_in,
                              void* d_out, int out_size, void* d_ws, size_t ws_size,
                              hipStream_t stream) {
    const float* features = (const float*)d_in[0];
    const float* boxes    = (const float*)d_in[1];
    const float* mask     = (const float*)d_in[2];
    const float* conv_w   = (const float*)d_in[3];
    const float* conv_b   = (const float*)d_in[4];
    const float* bn_g     = (const float*)d_in[5];
    const float* bn_b     = (const float*)d_in[6];
    const float* bn_m     = (const float*)d_in[7];
    const float* bn_v     = (const float*)d_in[8];

    char* base   = (char*)d_ws;
    float* cf_t  = (float*)(base);
    bf16*  Wp    = (bf16*)(base + OFF_WP);
    float* scale = (float*)(base + OFF_SCALE);
    float* shift = (float*)(base + OFF_SHIFT);
    char*  Xq    = (char*)(base + OFF_XQ);
    float* out   = (float*)d_out;

    k_resize<<<392, 256, 0, stream>>>(features, cf_t);
    k_packw<<<4608, 256, 0, stream>>>(conv_w, conv_b, bn_g, bn_b, bn_m, bn_v, Wp, scale, shift);
    k_build<<<512, 256, 0, stream>>>(mask, boxes, cf_t, Xq);
    k_conv<<<1024, 256, 0, stream>>>(Wp, Xq, scale, shift, out);
}